// Round 18
// baseline (1366.984 us; speedup 1.0000x reference)
//
#include <hip/hip_runtime.h>
#include <hip/hip_bf16.h>
#include <stdint.h>

namespace {

constexpr int TT    = 8192;
constexpr int BB    = 16;
constexpr int CD    = 256;
constexpr int FD    = 1024;
constexpr int CAPY  = 1280;
constexpr int NTOK  = BB * TT;   // 131072
constexpr int NPAIR = BB * 8;    // 128
constexpr int FLAGCAP1 = 16384;
constexpr int FLAGCAP2 = 4096;
constexpr int TPC   = 32768;     // tokens per chunk
constexpr int NCHUNK = NTOK / TPC;

using f4 = float4;
typedef __attribute__((ext_vector_type(8))) short short8;       // 8 bf16
typedef __attribute__((ext_vector_type(8))) _Float16 half8;     // 8 f16
typedef __attribute__((ext_vector_type(4))) float f32x4;

#define MFMA_BF __builtin_amdgcn_mfma_f32_16x16x32_bf16
#define MFMA_HF __builtin_amdgcn_mfma_f32_16x16x32_f16

__device__ __forceinline__ f4 ld4(const float* p){ return *(const f4*)p; }

__device__ __forceinline__ unsigned short bfh(float x){
  uint32_t u = __float_as_uint(x);
  return (unsigned short)((u + 0x7fffu + ((u >> 16) & 1u)) >> 16);
}
__device__ __forceinline__ float b2f(unsigned short h){
  return __uint_as_float(((uint32_t)h) << 16);
}
__device__ __forceinline__ uint32_t packbf(float x){
  uint32_t u = __float_as_uint(x);
  uint32_t hi = (u + 0x7fffu + ((u >> 16) & 1u)) & 0xffff0000u;
  float r = x - __uint_as_float(hi);
  uint32_t v = __float_as_uint(r);
  uint32_t lo = ((v + 0x7fffu + ((v >> 16) & 1u)) >> 16) & 0xffffu;
  return hi | lo;
}
__device__ __forceinline__ unsigned short f16b(float v){
  union { _Float16 h; unsigned short u; } U; U.h = (_Float16)v; return U.u;
}
__device__ __forceinline__ void unpack8(const uint32_t* p, short8& h, short8& l){
  uint4 a = *(const uint4*)p;
  uint4 b = *(const uint4*)(p + 4);
  union { uint32_t u[4]; short8 s; } H, L;
  H.u[0] = (a.y & 0xffff0000u) | (a.x >> 16);  L.u[0] = (a.y << 16) | (a.x & 0xffffu);
  H.u[1] = (a.w & 0xffff0000u) | (a.z >> 16);  L.u[1] = (a.w << 16) | (a.z & 0xffffu);
  H.u[2] = (b.y & 0xffff0000u) | (b.x >> 16);  L.u[2] = (b.y << 16) | (b.x & 0xffffu);
  H.u[3] = (b.w & 0xffff0000u) | (b.z >> 16);  L.u[3] = (b.w << 16) | (b.z & 0xffffu);
  h = H.s; l = L.s;
}

// async global->LDS, 16B per lane; LDS dest = wave-uniform base + lane*16
__device__ __forceinline__ void gload16(const unsigned short* g, unsigned short* l){
  __builtin_amdgcn_global_load_lds(
      (const __attribute__((address_space(1))) void*)reinterpret_cast<uintptr_t>(g),
      (__attribute__((address_space(3))) void*)(uint32_t)reinterpret_cast<uintptr_t>(l),
      16, 0, 0);
}

// ---------------- prep: x fp32 -> f16 row-major copy ----------------
__global__ __launch_bounds__(256)
void x_to_f16(const float* __restrict__ x, unsigned short* __restrict__ o)
{
  const size_t i = (size_t)blockIdx.x*256 + threadIdx.x;   // 16 floats each
  const float* p = x + i*16;
  f4 a = ld4(p), b = ld4(p+4), c = ld4(p+8), d = ld4(p+12);
  union { unsigned short u[16]; uint4 q[2]; } U;
  U.u[0]=f16b(a.x); U.u[1]=f16b(a.y); U.u[2]=f16b(a.z); U.u[3]=f16b(a.w);
  U.u[4]=f16b(b.x); U.u[5]=f16b(b.y); U.u[6]=f16b(b.z); U.u[7]=f16b(b.w);
  U.u[8]=f16b(c.x); U.u[9]=f16b(c.y); U.u[10]=f16b(c.z); U.u[11]=f16b(c.w);
  U.u[12]=f16b(d.x);U.u[13]=f16b(d.y);U.u[14]=f16b(d.z); U.u[15]=f16b(d.w);
  *(uint4*)(o + i*16)     = U.q[0];
  *(uint4*)(o + i*16 + 8) = U.q[1];
}

// ---------------- prep: fp32 [R][C] -> bf16 hi/lo [C][R] ----------------
__global__ __launch_bounds__(256)
void prep_transpose(const float* __restrict__ in, unsigned short* __restrict__ oh,
                    unsigned short* __restrict__ ol, int R, int C)
{
  __shared__ float T[32][33];
  const int tx = threadIdx.x & 31, ty = threadIdx.x >> 5;
  const size_t bs = (size_t)R * C;
  const float* ib = in + bs * blockIdx.z;
  unsigned short* ohb = oh + bs * blockIdx.z;
  unsigned short* olb = ol + bs * blockIdx.z;
  const int r0 = blockIdx.y * 32, c0 = blockIdx.x * 32;
  #pragma unroll
  for (int j = 0; j < 4; ++j)
    T[ty + 8*j][tx] = ib[(size_t)(r0 + ty + 8*j)*C + c0 + tx];
  __syncthreads();
  #pragma unroll
  for (int j = 0; j < 4; ++j){
    float v = T[tx][ty + 8*j];
    unsigned short h = bfh(v);
    unsigned short lo = bfh(v - b2f(h));
    size_t o = (size_t)(c0 + ty + 8*j)*R + r0 + tx;
    ohb[o] = h; olb[o] = lo;
  }
}

// ---------------- prep: fp32 [R][C] -> f16 [C][R] ----------------
__global__ __launch_bounds__(256)
void prep_transpose_f16(const float* __restrict__ in, unsigned short* __restrict__ o, int R, int C)
{
  __shared__ float T[32][33];
  const int tx = threadIdx.x & 31, ty = threadIdx.x >> 5;
  const size_t bs = (size_t)R * C;
  const float* ib = in + bs * blockIdx.z;
  unsigned short* ob = o + bs * blockIdx.z;
  const int r0 = blockIdx.y * 32, c0 = blockIdx.x * 32;
  #pragma unroll
  for (int j = 0; j < 4; ++j)
    T[ty + 8*j][tx] = ib[(size_t)(r0 + ty + 8*j)*C + c0 + tx];
  __syncthreads();
  #pragma unroll
  for (int j = 0; j < 4; ++j)
    ob[(size_t)(c0 + ty + 8*j)*R + r0 + tx] = f16b(T[tx][ty + 8*j]);
}

// ================= K1a: GEMM_A  xF16@W1 -> relu -> H1, double-buffered staging =================
__global__ __launch_bounds__(256, 2)
void gemm_a(const unsigned short* __restrict__ xF, int tok0,
            const unsigned short* __restrict__ W1F,   // [1024][256] f16 (W1^T)
            const float* __restrict__ b1,
            unsigned short* __restrict__ H1)          // chunk-local [TPC][1024] f16
{
  __shared__ unsigned short smem[32768];   // 64 KB: 2 x (As 16KB + Bs 16KB)
  const int tid = threadIdx.x;
  const int w = tid >> 6, lane = tid & 63, l15 = lane & 15, l4 = lane >> 4;
  const int wm = w >> 1, wn = w & 1;
  const int bid = ((int)blockIdx.x & 7) * ((int)gridDim.x >> 3) + ((int)blockIdx.x >> 3);
  const int mt0 = (bid >> 3) * 128;
  const int nt0 = (bid & 7) * 128;
  const int row_s = tid >> 1, half = tid & 1;
  const int lrow = lane >> 3;
  const int srcAB = lrow*CD + (((lane & 7) ^ lrow) << 3);

  auto stage = [&](int buf, int ks){
    const unsigned short* abase = xF  + (size_t)(tok0 + mt0)*CD + ks*64;
    const unsigned short* bbase = W1F + (size_t)nt0*CD + ks*64;
    unsigned short* As_ = smem + buf*16384;
    unsigned short* Bs_ = As_ + 8192;
    #pragma unroll
    for (int i = 0; i < 4; ++i){
      const int r0 = w*32 + i*8;
      gload16(abase + (size_t)r0*CD + srcAB, As_ + r0*64);
      gload16(bbase + (size_t)r0*CD + srcAB, Bs_ + r0*64);
    }
  };

  f32x4 acc[4][4];
  #pragma unroll
  for (int mt = 0; mt < 4; ++mt)
    #pragma unroll
    for (int nt = 0; nt < 4; ++nt)
      acc[mt][nt] = (f32x4){0.f,0.f,0.f,0.f};

  stage(0, 0);
  __syncthreads();

  #pragma unroll 1
  for (int ks = 0; ks < 4; ++ks){          // K = 256
    const int cur = ks & 1;
    if (ks + 1 < 4) stage(cur ^ 1, ks + 1);   // issue next-tile loads (fly under MFMA)
    const unsigned short* As = smem + cur*16384;
    const unsigned short* Bs = As + 8192;
    #pragma unroll
    for (int kt = 0; kt < 2; ++kt){
      half8 af[4], bf[4];
      #pragma unroll
      for (int mt = 0; mt < 4; ++mt){
        const int r = 64*wm + 16*mt + l15;
        af[mt] = *(const half8*)&As[r*64 + (((kt*4 + l4) ^ (r & 7)) << 3)];
      }
      #pragma unroll
      for (int nt = 0; nt < 4; ++nt){
        const int r = 64*wn + 16*nt + l15;
        bf[nt] = *(const half8*)&Bs[r*64 + (((kt*4 + l4) ^ (r & 7)) << 3)];
      }
      #pragma unroll
      for (int mt = 0; mt < 4; ++mt)
        #pragma unroll
        for (int nt = 0; nt < 4; ++nt)
          acc[mt][nt] = MFMA_HF(af[mt], bf[nt], acc[mt][nt], 0,0,0);
    }
    __syncthreads();   // drains next-tile staging; protects buf reuse (2 barriers apart)
  }

  unsigned short* Cs = smem;               // [128][128] = 32 KB
  #pragma unroll
  for (int nt = 0; nt < 4; ++nt){
    const int ncol = 64*wn + 16*nt + l15;
    const float b1v = b1[nt0 + ncol];
    #pragma unroll
    for (int mt = 0; mt < 4; ++mt)
      #pragma unroll
      for (int r = 0; r < 4; ++r){
        const int tr = 64*wm + 16*mt + 4*l4 + r;
        Cs[tr*128 + ncol] = f16b(fmaxf(acc[mt][nt][r] + b1v, 0.f));
      }
  }
  __syncthreads();
  {
    unsigned short* dst = H1 + (size_t)(mt0 + row_s)*FD + nt0 + half*64;
    const unsigned short* src = Cs + row_s*128 + half*64;
    #pragma unroll
    for (int j = 0; j < 8; ++j) ((uint4*)dst)[j] = ((const uint4*)src)[j];
  }
}

// ================= K1b: GEMM_B  H1@W2 -> relu -> @W3 partials, double-buffered staging =================
__global__ __launch_bounds__(256, 2)
void gemm_b(const unsigned short* __restrict__ H1, int tok0,
            const unsigned short* __restrict__ W2F,   // [1024][1024] f16 (W2^T)
            const float* __restrict__ b2,
            const float* __restrict__ W3,             // [1024][8]
            float* __restrict__ plg)                  // [8][NTOK][8]
{
  __shared__ unsigned short smem[32768];   // 64 KB: 2 x (As 16KB + Bs 16KB)
  const int tid = threadIdx.x;
  const int w = tid >> 6, lane = tid & 63, l15 = lane & 15, l4 = lane >> 4;
  const int wm = w >> 1, wn = w & 1;
  const int bid = ((int)blockIdx.x & 7) * ((int)gridDim.x >> 3) + ((int)blockIdx.x >> 3);
  const int ntile = bid & 7;
  const int mt0 = (bid >> 3) * 128;
  const int nt0 = ntile * 128;
  const int row_s = tid >> 1, half = tid & 1;
  const int lrow = lane >> 3;
  const int srcAB = lrow*FD + (((lane & 7) ^ lrow) << 3);

  auto stage = [&](int buf, int ks){
    const unsigned short* abase = H1  + (size_t)mt0*FD + ks*64;
    const unsigned short* bbase = W2F + (size_t)nt0*FD + ks*64;
    unsigned short* As_ = smem + buf*16384;
    unsigned short* Bs_ = As_ + 8192;
    #pragma unroll
    for (int i = 0; i < 4; ++i){
      const int r0 = w*32 + i*8;
      gload16(abase + (size_t)r0*FD + srcAB, As_ + r0*64);
      gload16(bbase + (size_t)r0*FD + srcAB, Bs_ + r0*64);
    }
  };

  f32x4 acc[4][4];
  #pragma unroll
  for (int mt = 0; mt < 4; ++mt)
    #pragma unroll
    for (int nt = 0; nt < 4; ++nt)
      acc[mt][nt] = (f32x4){0.f,0.f,0.f,0.f};

  stage(0, 0);
  __syncthreads();

  #pragma unroll 1
  for (int ks = 0; ks < 16; ++ks){          // K = 1024
    const int cur = ks & 1;
    if (ks + 1 < 16) stage(cur ^ 1, ks + 1);
    const unsigned short* As = smem + cur*16384;
    const unsigned short* Bs = As + 8192;
    #pragma unroll
    for (int kt = 0; kt < 2; ++kt){
      half8 af[4], bf[4];
      #pragma unroll
      for (int mt = 0; mt < 4; ++mt){
        const int r = 64*wm + 16*mt + l15;
        af[mt] = *(const half8*)&As[r*64 + (((kt*4 + l4) ^ (r & 7)) << 3)];
      }
      #pragma unroll
      for (int nt = 0; nt < 4; ++nt){
        const int r = 64*wn + 16*nt + l15;
        bf[nt] = *(const half8*)&Bs[r*64 + (((kt*4 + l4) ^ (r & 7)) << 3)];
      }
      #pragma unroll
      for (int mt = 0; mt < 4; ++mt)
        #pragma unroll
        for (int nt = 0; nt < 4; ++nt)
          acc[mt][nt] = MFMA_HF(af[mt], bf[nt], acc[mt][nt], 0,0,0);
    }
    __syncthreads();
  }

  float* lgs = (float*)smem;                // 4 KB
  *(f4*)&lgs[tid*4] = (f4){0.f,0.f,0.f,0.f};
  __syncthreads();

  #pragma unroll
  for (int mt = 0; mt < 4; ++mt){           // FULL unroll: static acc index (rule #20)
    float lp[4][8];
    #pragma unroll
    for (int r = 0; r < 4; ++r)
      #pragma unroll
      for (int e = 0; e < 8; ++e) lp[r][e] = 0.f;
    #pragma unroll
    for (int nt = 0; nt < 4; ++nt){
      const int n2 = nt0 + 64*wn + 16*nt + l15;
      const float b2v = b2[n2];
      f4 wa = ld4(W3 + n2*8), wb3 = ld4(W3 + n2*8 + 4);
      const float w3s[8] = {wa.x,wa.y,wa.z,wa.w,wb3.x,wb3.y,wb3.z,wb3.w};
      #pragma unroll
      for (int r = 0; r < 4; ++r){
        float h2 = fmaxf(acc[mt][nt][r] + b2v, 0.f);
        #pragma unroll
        for (int e = 0; e < 8; ++e)
          lp[r][e] = fmaf(h2, w3s[e], lp[r][e]);
      }
    }
    #pragma unroll
    for (int off = 1; off < 16; off <<= 1)
      #pragma unroll
      for (int r = 0; r < 4; ++r)
        #pragma unroll
        for (int e = 0; e < 8; ++e)
          lp[r][e] += __shfl_xor(lp[r][e], off);
    if (l15 == 0){
      #pragma unroll
      for (int r = 0; r < 4; ++r){
        const int row = 64*wm + 16*mt + 4*l4 + r;
        #pragma unroll
        for (int e = 0; e < 8; ++e)
          atomicAdd(&lgs[row*8 + e], lp[r][e]);
      }
    }
  }
  __syncthreads();
  {
    f4 v = *(const f4*)&lgs[row_s*8 + half*4];
    *(f4*)(plg + ((size_t)ntile*NTOK + tok0 + mt0 + row_s)*8 + half*4) = v;
  }
}

// ================= K1c: reduce partial logits, top-2, flag near-ties =================
__global__ __launch_bounds__(256)
void top2_kernel(const float* __restrict__ plg, const float* __restrict__ b3,
                 int2* __restrict__ topE, float2* __restrict__ topW,
                 int* __restrict__ flagList, int* __restrict__ flagCnt)
{
  const int tok = blockIdx.x*256 + threadIdx.x;
  float l[8];
  #pragma unroll
  for (int e = 0; e < 8; ++e) l[e] = b3[e];
  #pragma unroll
  for (int s = 0; s < 8; ++s){
    const float* p = plg + ((size_t)s*NTOK + tok)*8;
    f4 p0 = ld4(p), p1 = ld4(p + 4);
    l[0]+=p0.x; l[1]+=p0.y; l[2]+=p0.z; l[3]+=p0.w;
    l[4]+=p1.x; l[5]+=p1.y; l[6]+=p1.z; l[7]+=p1.w;
  }
  int e1 = 0; float v1 = l[0];
  #pragma unroll
  for (int e = 1; e < 8; ++e){ if (l[e] > v1){ v1 = l[e]; e1 = e; } }
  int e2 = 0; float v2 = -3.0e38f;
  #pragma unroll
  for (int e = 0; e < 8; ++e){ if (e != e1 && l[e] > v2){ v2 = l[e]; e2 = e; } }
  float v3 = -3.0e38f;
  #pragma unroll
  for (int e = 0; e < 8; ++e){ if (e != e1 && e != e2 && l[e] > v3) v3 = l[e]; }
  float s = 0.f;
  #pragma unroll
  for (int e = 0; e < 8; ++e) s += expf(l[e]-v1);
  topE[tok] = make_int2(e1, e2);
  topW[tok] = make_float2(1.0f/s, expf(v2 - v1)/s);
  if (v2 - v3 < 5e-4f){
    int i = atomicAdd(flagCnt, 1);
    if (i < FLAGCAP1) flagList[i] = tok;
  }
}

// ---------------- K2: bf16 3-term re-route of flagged tokens, M=32 ----------------
__global__ __launch_bounds__(512, 2)
void router_fix1(const float* __restrict__ x,
                 const unsigned short* __restrict__ W1Th, const unsigned short* __restrict__ W1Tl,
                 const float* __restrict__ b1,
                 const unsigned short* __restrict__ W2Th, const unsigned short* __restrict__ W2Tl,
                 const float* __restrict__ b2,
                 const float* __restrict__ W3, const float* __restrict__ b3,
                 const int* __restrict__ flagList, const int* __restrict__ flagCnt,
                 int2* __restrict__ topE, float2* __restrict__ topW,
                 int* __restrict__ flagList2, int* __restrict__ flagCnt2)
{
  int cnt = *flagCnt; if (cnt > FLAGCAP1) cnt = FLAGCAP1;
  const int s0 = blockIdx.x * 32;
  if (s0 >= cnt) return;

  __shared__ uint32_t Xp[32*256];
  __shared__ uint32_t Hp[32*128];
  __shared__ float lgs[32*8];
  __shared__ int sTok[32];
  const int tid = threadIdx.x;
  const int w = tid >> 6, lane = tid & 63;
  const int l15 = lane & 15, l4 = lane >> 4;
  const int swz = l15 & 7;

  if (tid < 32){
    const int s = s0 + tid;
    sTok[tid] = (s < cnt) ? flagList[s] : flagList[s0];
  }
  if (tid < 256) lgs[tid] = 0.f;
  __syncthreads();
  {
    const int row = tid >> 4, cb = (tid & 15) * 2;
    const float* rp = x + (size_t)sTok[row]*CD + cb*8;
    #pragma unroll
    for (int g = 0; g < 2; ++g){
      f4 a = ld4(rp + g*8), bq = ld4(rp + g*8 + 4);
      uint32_t* dst = &Xp[row*256 + (((cb + g) ^ (row & 7)) << 3)];
      *(uint4*)dst     = make_uint4(packbf(a.x),packbf(a.y),packbf(a.z),packbf(a.w));
      *(uint4*)(dst+4) = make_uint4(packbf(bq.x),packbf(bq.y),packbf(bq.z),packbf(bq.w));
    }
  }
  __syncthreads();

  f32x4 acc2[2][8];
  #pragma unroll
  for (int mt = 0; mt < 2; ++mt)
    #pragma unroll
    for (int nt = 0; nt < 8; ++nt)
      acc2[mt][nt] = (f32x4){0.f,0.f,0.f,0.f};

  #pragma unroll 1
  for (int kc = 0; kc < 8; ++kc){
    f32x4 acc1[2] = {(f32x4){0,0,0,0},(f32x4){0,0,0,0}};
    const int n1g = kc*128 + 16*w + l15;
    const size_t wb1 = (size_t)n1g * 256;
    #pragma unroll
    for (int kt = 0; kt < 8; ++kt){
      short8 ah[2], al[2];
      #pragma unroll
      for (int mt = 0; mt < 2; ++mt)
        unpack8(&Xp[(mt*16 + l15)*256 + ((((kt<<2) + l4) ^ swz) << 3)], ah[mt], al[mt]);
      const int kb = kt*32 + 8*l4;
      short8 bh = *(const short8*)&W1Th[wb1 + kb];
      short8 bl = *(const short8*)&W1Tl[wb1 + kb];
      #pragma unroll
      for (int mt = 0; mt < 2; ++mt)
        acc1[mt] = MFMA_BF(ah[mt], bh, MFMA_BF(ah[mt], bl, MFMA_BF(al[mt], bh, acc1[mt],0,0,0),0,0,0),0,0,0);
    }
    __syncthreads();
    {
      const float b1v = b1[n1g];
      const int c = 16*w + l15, ch = c >> 3, co = c & 7;
      #pragma unroll
      for (int mt = 0; mt < 2; ++mt)
        #pragma unroll
        for (int r = 0; r < 4; ++r){
          const int row = mt*16 + 4*l4 + r;
          Hp[row*128 + ((ch ^ (row & 7)) << 3) + co] = packbf(fmaxf(acc1[mt][r] + b1v, 0.f));
        }
    }
    __syncthreads();
    #pragma unroll
    for (int kt = 0; kt < 4; ++kt){
      short8 ah[2], al[2];
      #pragma unroll
      for (int mt = 0; mt < 2; ++mt)
        unpack8(&Hp[(mt*16 + l15)*128 + ((((kt<<2) + l4) ^ swz) << 3)], ah[mt], al[mt]);
      const size_t kg = (size_t)(kc*128 + kt*32 + 8*l4);
      #pragma unroll
      for (int nt = 0; nt < 8; ++nt){
        const size_t wb2 = (size_t)(128*w + 16*nt + l15) * 1024 + kg;
        short8 bh = *(const short8*)&W2Th[wb2];
        short8 bl = *(const short8*)&W2Tl[wb2];
        #pragma unroll
        for (int mt = 0; mt < 2; ++mt)
          acc2[mt][nt] = MFMA_BF(ah[mt], bh, MFMA_BF(ah[mt], bl, MFMA_BF(al[mt], bh, acc2[mt][nt],0,0,0),0,0,0),0,0,0);
      }
    }
  }

  #pragma unroll
  for (int mt = 0; mt < 2; ++mt){
    float lp[4][8];
    #pragma unroll
    for (int r = 0; r < 4; ++r)
      #pragma unroll
      for (int e = 0; e < 8; ++e) lp[r][e] = 0.f;
    #pragma unroll
    for (int nt = 0; nt < 8; ++nt){
      const int n2 = 128*w + 16*nt + l15;
      const float b2v = b2[n2];
      f4 wa = ld4(W3 + n2*8), wb3 = ld4(W3 + n2*8 + 4);
      const float w3s[8] = {wa.x,wa.y,wa.z,wa.w,wb3.x,wb3.y,wb3.z,wb3.w};
      #pragma unroll
      for (int r = 0; r < 4; ++r){
        float h2 = fmaxf(acc2[mt][nt][r] + b2v, 0.f);
        #pragma unroll
        for (int e = 0; e < 8; ++e)
          lp[r][e] = fmaf(h2, w3s[e], lp[r][e]);
      }
    }
    #pragma unroll
    for (int off = 1; off < 16; off <<= 1)
      #pragma unroll
      for (int r = 0; r < 4; ++r)
        #pragma unroll
        for (int e = 0; e < 8; ++e)
          lp[r][e] += __shfl_xor(lp[r][e], off);
    if (l15 == 0){
      #pragma unroll
      for (int r = 0; r < 4; ++r){
        const int row = mt*16 + 4*l4 + r;
        #pragma unroll
        for (int e = 0; e < 8; ++e)
          atomicAdd(&lgs[row*8 + e], lp[r][e]);
      }
    }
  }
  __syncthreads();

  if (tid < 32 && s0 + tid < cnt){
    const int tok = sTok[tid];
    float l[8];
    #pragma unroll
    for (int e = 0; e < 8; ++e) l[e] = lgs[tid*8 + e] + b3[e];
    int e1 = 0; float v1 = l[0];
    #pragma unroll
    for (int e = 1; e < 8; ++e){ if (l[e] > v1){ v1 = l[e]; e1 = e; } }
    int e2 = 0; float v2 = -3.0e38f;
    #pragma unroll
    for (int e = 0; e < 8; ++e){ if (e != e1 && l[e] > v2){ v2 = l[e]; e2 = e; } }
    float v3 = -3.0e38f;
    #pragma unroll
    for (int e = 0; e < 8; ++e){ if (e != e1 && e != e2 && l[e] > v3) v3 = l[e]; }
    float s = 0.f;
    #pragma unroll
    for (int e = 0; e < 8; ++e) s += expf(l[e]-v1);
    topE[tok] = make_int2(e1, e2);
    topW[tok] = make_float2(1.0f/s, expf(v2 - v1)/s);
    if (v2 - v3 < 1e-4f){
      int i = atomicAdd(flagCnt2, 1);
      if (i < FLAGCAP2) flagList2[i] = tok;
    }
  }
}

// ---------------- K3: exact fp32 recompute for residual near-ties ----------------
__global__ __launch_bounds__(256)
void router_fixup(const float* __restrict__ x,
                  const float* __restrict__ W1, const float* __restrict__ b1,
                  const float* __restrict__ W2, const float* __restrict__ b2,
                  const float* __restrict__ W3, const float* __restrict__ b3,
                  const int* __restrict__ flagList, const int* __restrict__ flagCnt,
                  int2* __restrict__ topE, float2* __restrict__ topW)
{
  int n = *flagCnt; if (n > FLAGCAP2) n = FLAGCAP2;
  if ((int)blockIdx.x >= n) return;
  const int t = flagList[blockIdx.x];
  __shared__ float xs[256];
  __shared__ float h1[1024];
  __shared__ float h2[1024];
  __shared__ float lgf[8];
  const int tid = threadIdx.x;
  xs[tid] = x[(size_t)t*256 + tid];
  __syncthreads();
  {
    float a0=b1[tid], a1=b1[tid+256], a2=b1[tid+512], a3=b1[tid+768];
    for (int k = 0; k < 256; ++k){
      const float xv = xs[k];
      const float* wr = W1 + (size_t)k*1024;
      a0 = fmaf(xv, wr[tid],     a0);
      a1 = fmaf(xv, wr[tid+256], a1);
      a2 = fmaf(xv, wr[tid+512], a2);
      a3 = fmaf(xv, wr[tid+768], a3);
    }
    h1[tid]=fmaxf(a0,0.f); h1[tid+256]=fmaxf(a1,0.f); h1[tid+512]=fmaxf(a2,0.f); h1[tid+768]=fmaxf(a3,0.f);
  }
  __syncthreads();
  {
    float a0=b2[tid], a1=b2[tid+256], a2=b2[tid+512], a3=b2[tid+768];
    for (int k = 0; k < 1024; ++k){
      const float hv = h1[k];
      const float* wr = W2 + (size_t)k*1024;
      a0 = fmaf(hv, wr[tid],     a0);
      a1 = fmaf(hv, wr[tid+256], a1);
      a2 = fmaf(hv, wr[tid+512], a2);
      a3 = fmaf(hv, wr[tid+768], a3);
    }
    h2[tid]=fmaxf(a0,0.f); h2[tid+256]=fmaxf(a1,0.f); h2[tid+512]=fmaxf(a2,0.f); h2[tid+768]=fmaxf(a3,0.f);
  }
  __syncthreads();
  {
    const int e = tid >> 5, s = tid & 31;
    float p = 0.f;
    for (int k = s*32; k < s*32+32; ++k) p = fmaf(h2[k], W3[(size_t)k*8 + e], p);
    #pragma unroll
    for (int off = 1; off < 32; off <<= 1) p += __shfl_xor(p, off);
    if (s == 0) lgf[e] = p + b3[e];
  }
  __syncthreads();
  if (tid == 0){
    float l[8];
    #pragma unroll
    for (int e=0;e<8;++e) l[e] = lgf[e];
    int e1 = 0; float v1 = l[0];
    #pragma unroll
    for (int e=1;e<8;++e){ if (l[e] > v1){ v1 = l[e]; e1 = e; } }
    int e2 = 0; float v2 = -3.0e38f;
    #pragma unroll
    for (int e=0;e<8;++e){ if (e != e1 && l[e] > v2){ v2 = l[e]; e2 = e; } }
    float s = 0.f;
    #pragma unroll
    for (int e=0;e<8;++e) s += expf(l[e]-v1);
    topE[t] = make_int2(e1, e2);
    topW[t] = make_float2(1.0f/s, expf(v2 - v1)/s);
  }
}

// ---------------- K4: per-(b,e) count, capacity mask, stable compaction ----------------
__global__ __launch_bounds__(256)
void route_compact(const int2* __restrict__ topE, const float2* __restrict__ topW,
                   int* __restrict__ listIdx, float* __restrict__ listW, int* __restrict__ kcnt)
{
  const int blk = blockIdx.x;
  const int b = blk >> 3, e = blk & 7;
  const int2* te = topE + (size_t)b*TT;
  const float2* tw = topW + (size_t)b*TT;
  __shared__ unsigned kmask[256];
  __shared__ int wTot[4], wTot2[4];
  __shared__ int s_cnt, s_baseRank, s_baseSlot;
  const int tid = threadIdx.x;
  const int lane = tid & 63, wid = tid >> 6;

  if (tid == 0){ s_cnt = 0; s_baseRank = 0; s_baseSlot = 0; }
  kmask[tid & 255] = 0;
  __syncthreads();

  int c = 0;
  for (int t = tid; t < TT; t += 256){
    int2 v = te[t];
    c += (v.x == e) || (v.y == e);
  }
  #pragma unroll
  for (int off = 32; off; off >>= 1) c += __shfl_xor(c, off);
  if (lane == 0) atomicAdd(&s_cnt, c);
  __syncthreads();
  const int cnt = s_cnt;

  if (cnt > CAPY){
    for (int i = tid; i < CAPY; i += 256){
      float t1 = (float)i * (float)(cnt - 1);
      float t2 = t1 / 1279.0f;
      int r = (int)floorf(t2);
      atomicOr(&kmask[r >> 5], 1u << (r & 31));
    }
  }
  __syncthreads();

  for (int tile = 0; tile < 32; ++tile){
    const int t = tile*256 + tid;
    const int2 v = te[t];
    const bool sel = (v.x == e) || (v.y == e);
    const float2 wv = tw[t];
    const float w = (v.x == e) ? wv.x : wv.y;

    unsigned long long mSel = __ballot(sel);
    const int lpfx = __popcll(mSel & ((1ull << lane) - 1ull));
    if (lane == 0) wTot[wid] = __popcll(mSel);
    __syncthreads();
    int wpfx = 0;
    for (int wdx = 0; wdx < wid; ++wdx) wpfx += wTot[wdx];
    const int rank = s_baseRank + wpfx + lpfx;

    const bool kept = sel && (cnt <= CAPY || ((kmask[rank >> 5] >> (rank & 31)) & 1u));
    unsigned long long mK = __ballot(kept);
    const int lpfx2 = __popcll(mK & ((1ull << lane) - 1ull));
    if (lane == 0) wTot2[wid] = __popcll(mK);
    __syncthreads();
    int wpfx2 = 0;
    for (int wdx = 0; wdx < wid; ++wdx) wpfx2 += wTot2[wdx];
    const int slot = s_baseSlot + wpfx2 + lpfx2;

    if (kept){
      listIdx[(size_t)blk*CAPY + slot] = t;
      listW [(size_t)blk*CAPY + slot] = w;
    }
    __syncthreads();
    if (tid == 0){
      int a = 0, q = 0;
      for (int wdx = 0; wdx < 4; ++wdx){ a += wTot[wdx]; q += wTot2[wdx]; }
      s_baseRank += a; s_baseSlot += q;
    }
    __syncthreads();
  }
  if (tid == 0) kcnt[blk] = s_baseSlot;
}

// ---------------- K5: expert FFN, M=64, f16 MFMA, e-major grid ----------------
__global__ __launch_bounds__(512, 3)
void expert_mfma(const float* __restrict__ x,
                 const unsigned short* __restrict__ WiF, const float* __restrict__ ebi,
                 const unsigned short* __restrict__ WoF, const float* __restrict__ ebo,
                 const int* __restrict__ listIdx, const float* __restrict__ listW,
                 const int* __restrict__ kcnt, float* __restrict__ out)
{
  const int q = blockIdx.y;
  const int e = q >> 4, b = q & 15;
  const int pair = b*8 + e;
  const int kc_n = kcnt[pair];
  const int s0 = blockIdx.x * 64;
  if (s0 >= kc_n) return;

  __shared__ unsigned short Xf[64*256];
  __shared__ unsigned short Hf[64*128];
  __shared__ int sTok[64];
  __shared__ float sG[64];
  const int tid = threadIdx.x;
  const int w = tid >> 6, lane = tid & 63;
  const int l15 = lane & 15, l4 = lane >> 4;
  const int swz = l15 & 7;

  if (tid < 64){
    const int s = s0 + tid;
    const bool v = s < kc_n;
    sTok[tid] = v ? listIdx[(size_t)pair*CAPY + s] : -1;
    sG[tid]   = v ? listW [(size_t)pair*CAPY + s] : 0.f;
  }
  __syncthreads();
  {
    const int row = tid >> 3, cb = (tid & 7) * 4;
    int tk = sTok[row]; if (tk < 0) tk = 0;
    const float* rp = x + ((size_t)b*TT + tk)*CD + cb*8;
    #pragma unroll
    for (int g = 0; g < 4; ++g){
      f4 a = ld4(rp + g*8), bq = ld4(rp + g*8 + 4);
      union { unsigned short u[8]; short8 s; } U;
      U.u[0]=f16b(a.x); U.u[1]=f16b(a.y); U.u[2]=f16b(a.z); U.u[3]=f16b(a.w);
      U.u[4]=f16b(bq.x);U.u[5]=f16b(bq.y);U.u[6]=f16b(bq.z);U.u[7]=f16b(bq.w);
      *(short8*)&Xf[row*256 + (((cb + g) ^ (row & 7)) << 3)] = U.s;
    }
  }
  __syncthreads();

  const unsigned short* Wi = WiF + (size_t)e*FD*CD;
  const unsigned short* Wo = WoF + (size_t)e*CD*FD;

  f32x4 accO[4][2];
  #pragma unroll
  for (int mt = 0; mt < 4; ++mt)
    #pragma unroll
    for (int nt = 0; nt < 2; ++nt)
      accO[mt][nt] = (f32x4){0.f,0.f,0.f,0.f};

  #pragma unroll 1
  for (int kc = 0; kc < 8; ++kc){
    f32x4 acc1[4] = {(f32x4){0,0,0,0},(f32x4){0,0,0,0},(f32x4){0,0,0,0},(f32x4){0,0,0,0}};
    const int n1g = kc*128 + 16*w + l15;
    const size_t wbi = (size_t)n1g * 256;
    #pragma unroll
    for (int kt = 0; kt < 8; ++kt){
      half8 av[4];
      #pragma unroll
      for (int mt = 0; mt < 4; ++mt)
        av[mt] = *(const half8*)&Xf[(mt*16 + l15)*256 + ((((kt<<2) + l4) ^ swz) << 3)];
      half8 bf = *(const half8*)&Wi[wbi + kt*32 + 8*l4];
      #pragma unroll
      for (int mt = 0; mt < 4; ++mt)
        acc1[mt] = MFMA_HF(av[mt], bf, acc1[mt], 0,0,0);
    }
    __syncthreads();
    {
      const float biv = ebi[e*FD + n1g];
      const int c = 16*w + l15, ch = c >> 3, co = c & 7;
      #pragma unroll
      for (int mt = 0; mt < 4; ++mt)
        #pragma unroll
        for (int r = 0; r < 4; ++r){
          const int row = mt*16 + 4*l4 + r;
          Hf[row*128 + ((ch ^ (row & 7)) << 3) + co] = f16b(fmaxf(acc1[mt][r] + biv, 0.f));
        }
    }
    __syncthreads();
    #pragma unroll
    for (int kt = 0; kt < 4; ++kt){
      half8 av[4];
      #pragma unroll
      for (int mt = 0; mt < 4; ++mt)
        av[mt] = *(const half8*)&Hf[(mt*16 + l15)*128 + ((((kt<<2) + l4) ^ swz) << 3)];
      const size_t kg = (size_t)(kc*128 + kt*32 + 8*l4);
      #pragma unroll
      for (int nt = 0; nt < 2; ++nt){
        const int n = 32*w + 16*nt + l15;
        half8 bf = *(const half8*)&Wo[(size_t)n*1024 + kg];
        #pragma unroll
        for (int mt = 0; mt < 4; ++mt)
          accO[mt][nt] = MFMA_HF(av[mt], bf, accO[mt][nt], 0,0,0);
      }
    }
  }

  #pragma unroll
  for (int mt = 0; mt < 4; ++mt)
    #pragma unroll
    for (int r = 0; r < 4; ++r){
      const int row = mt*16 + 4*l4 + r;
      const int tk = sTok[row];
      if (tk >= 0){
        const float g = sG[row];
        #pragma unroll
        for (int nt = 0; nt < 2; ++nt){
          const int n = 32*w + 16*nt + l15;
          atomicAdd(out + ((size_t)b*TT + tk)*CD + n, (accO[mt][nt][r] + ebo[e*CD + n]) * g);
        }
      }
    }
}

} // namespace

extern "C" void kernel_launch(void* const* d_in, const int* in_sizes, int n_in,
                              void* d_out, int out_size, void* d_ws, size_t ws_size,
                              hipStream_t stream)
{
  const float* x   = (const float*)d_in[0];
  const float* rW1 = (const float*)d_in[1];
  const float* rb1 = (const float*)d_in[2];
  const float* rW2 = (const float*)d_in[3];
  const float* rb2 = (const float*)d_in[4];
  const float* rW3 = (const float*)d_in[5];
  const float* rb3 = (const float*)d_in[6];
  const float* eWi = (const float*)d_in[7];
  const float* ebi = (const float*)d_in[8];
  const float* eWo = (const float*)d_in[9];
  const float* ebo = (const float*)d_in[10];
  (void)in_sizes; (void)n_in; (void)ws_size;

  char* ws = (char*)d_ws;
  size_t off = 0;
  auto carve = [&](size_t bytes)->char*{ char* p = ws + off; off += (bytes + 255) & ~(size_t)255; return p; };
  unsigned short* W1F  = (unsigned short*)carve((size_t)FD*CD*2);
  unsigned short* W2F  = (unsigned short*)carve((size_t)FD*FD*2);
  unsigned short* W1Th = (unsigned short*)carve((size_t)FD*CD*2);
  unsigned short* W1Tl = (unsigned short*)carve((size_t)FD*CD*2);
  unsigned short* W2Th = (unsigned short*)carve((size_t)FD*FD*2);
  unsigned short* W2Tl = (unsigned short*)carve((size_t)FD*FD*2);
  unsigned short* WiF  = (unsigned short*)carve((size_t)8*FD*CD*2);
  unsigned short* WoF  = (unsigned short*)carve((size_t)8*CD*FD*2);
  unsigned short* xF16 = (unsigned short*)carve((size_t)NTOK*CD*2);         // 67 MB
  unsigned short* H1   = (unsigned short*)carve((size_t)TPC*FD*2);          // 67 MB
  float*  plg     = (float*)carve((size_t)8*NTOK*8*sizeof(float));          // 33.5 MB
  int2*   topE    = (int2*)carve((size_t)NTOK*sizeof(int2));
  float2* topW    = (float2*)carve((size_t)NTOK*sizeof(float2));
  int*    listIdx = (int*)carve((size_t)NPAIR*CAPY*sizeof(int));
  float*  listW   = (float*)carve((size_t)NPAIR*CAPY*sizeof(float));
  int*    kcnt    = (int*)carve((size_t)NPAIR*sizeof(int));
  int*    flagCnt = (int*)carve(256);
  int*    flagCnt2= (int*)carve(256);
  int*    flagList= (int*)carve((size_t)FLAGCAP1*sizeof(int));
  int*    flagList2=(int*)carve((size_t)FLAGCAP2*sizeof(int));

  float* out = (float*)d_out;
  hipMemsetAsync(out, 0, (size_t)out_size*sizeof(float), stream);
  hipMemsetAsync(flagCnt, 0, sizeof(int), stream);
  hipMemsetAsync(flagCnt2, 0, sizeof(int), stream);

  x_to_f16<<<NTOK*CD/16/256, 256, 0, stream>>>(x, xF16);
  prep_transpose_f16<<<dim3(32, 8, 1), 256, 0, stream>>>(rW1, W1F, 256, 1024);
  prep_transpose_f16<<<dim3(32,32, 1), 256, 0, stream>>>(rW2, W2F, 1024, 1024);
  prep_transpose<<<dim3(32, 8, 1), 256, 0, stream>>>(rW1, W1Th, W1Tl, 256, 1024);
  prep_transpose<<<dim3(32,32, 1), 256, 0, stream>>>(rW2, W2Th, W2Tl, 1024, 1024);
  prep_transpose_f16<<<dim3(32, 8, 8), 256, 0, stream>>>(eWi, WiF, 256, 1024);
  prep_transpose_f16<<<dim3( 8,32, 8), 256, 0, stream>>>(eWo, WoF, 1024, 256);

  for (int c = 0; c < NCHUNK; ++c){
    gemm_a<<<(TPC/128)*8, 256, 0, stream>>>(xF16, c*TPC, W1F, rb1, H1);
    gemm_b<<<(TPC/128)*8, 256, 0, stream>>>(H1, c*TPC, W2F, rb2, rW3, plg);
  }
  top2_kernel<<<NTOK/256, 256, 0, stream>>>(plg, rb3, topE, topW, flagList, flagCnt);

  router_fix1<<<FLAGCAP1/32, 512, 0, stream>>>(x, W1Th, W1Tl, rb1, W2Th, W2Tl, rb2,
                                               rW3, rb3, flagList, flagCnt,
                                               topE, topW, flagList2, flagCnt2);
  router_fixup<<<FLAGCAP2, 256, 0, stream>>>(x, rW1, rb1, rW2, rb2, rW3, rb3,
                                             flagList2, flagCnt2, topE, topW);
  route_compact<<<NPAIR, 256, 0, stream>>>(topE, topW, listIdx, listW, kcnt);
  expert_mfma<<<dim3(CAPY/64, 128), 512, 0, stream>>>(x, WiF, ebi, WoF, ebo,
                                                      listIdx, listW, kcnt, out);
}

// Round 19
// 1320.876 us; speedup vs baseline: 1.0349x; 1.0349x over previous
//
#include <hip/hip_runtime.h>
#include <hip/hip_bf16.h>
#include <stdint.h>

namespace {

constexpr int TT    = 8192;
constexpr int BB    = 16;
constexpr int CD    = 256;
constexpr int FD    = 1024;
constexpr int CAPY  = 1280;
constexpr int NTOK  = BB * TT;   // 131072
constexpr int NPAIR = BB * 8;    // 128
constexpr int FLAGCAP1 = 16384;
constexpr int FLAGCAP2 = 4096;
constexpr int TPC   = 32768;     // tokens per chunk
constexpr int NCHUNK = NTOK / TPC;

using f4 = float4;
typedef __attribute__((ext_vector_type(8))) short short8;       // 8 bf16
typedef __attribute__((ext_vector_type(8))) _Float16 half8;     // 8 f16
typedef __attribute__((ext_vector_type(4))) float f32x4;

#define MFMA_BF __builtin_amdgcn_mfma_f32_16x16x32_bf16
#define MFMA_HF __builtin_amdgcn_mfma_f32_16x16x32_f16

__device__ __forceinline__ f4 ld4(const float* p){ return *(const f4*)p; }

__device__ __forceinline__ unsigned short bfh(float x){
  uint32_t u = __float_as_uint(x);
  return (unsigned short)((u + 0x7fffu + ((u >> 16) & 1u)) >> 16);
}
__device__ __forceinline__ float b2f(unsigned short h){
  return __uint_as_float(((uint32_t)h) << 16);
}
__device__ __forceinline__ uint32_t packbf(float x){
  uint32_t u = __float_as_uint(x);
  uint32_t hi = (u + 0x7fffu + ((u >> 16) & 1u)) & 0xffff0000u;
  float r = x - __uint_as_float(hi);
  uint32_t v = __float_as_uint(r);
  uint32_t lo = ((v + 0x7fffu + ((v >> 16) & 1u)) >> 16) & 0xffffu;
  return hi | lo;
}
__device__ __forceinline__ unsigned short f16b(float v){
  union { _Float16 h; unsigned short u; } U; U.h = (_Float16)v; return U.u;
}
__device__ __forceinline__ void unpack8(const uint32_t* p, short8& h, short8& l){
  uint4 a = *(const uint4*)p;
  uint4 b = *(const uint4*)(p + 4);
  union { uint32_t u[4]; short8 s; } H, L;
  H.u[0] = (a.y & 0xffff0000u) | (a.x >> 16);  L.u[0] = (a.y << 16) | (a.x & 0xffffu);
  H.u[1] = (a.w & 0xffff0000u) | (a.z >> 16);  L.u[1] = (a.w << 16) | (a.z & 0xffffu);
  H.u[2] = (b.y & 0xffff0000u) | (b.x >> 16);  L.u[2] = (b.y << 16) | (b.x & 0xffffu);
  H.u[3] = (b.w & 0xffff0000u) | (b.z >> 16);  L.u[3] = (b.w << 16) | (b.z & 0xffffu);
  h = H.s; l = L.s;
}

// async global->LDS, 16B per lane; LDS dest = wave-uniform base + lane*16
__device__ __forceinline__ void gload16(const unsigned short* g, unsigned short* l){
  __builtin_amdgcn_global_load_lds(
      (const __attribute__((address_space(1))) void*)reinterpret_cast<uintptr_t>(g),
      (__attribute__((address_space(3))) void*)(uint32_t)reinterpret_cast<uintptr_t>(l),
      16, 0, 0);
}

// ---------------- prep: x fp32 -> f16 row-major copy ----------------
__global__ __launch_bounds__(256)
void x_to_f16(const float* __restrict__ x, unsigned short* __restrict__ o)
{
  const size_t i = (size_t)blockIdx.x*256 + threadIdx.x;   // 16 floats each
  const float* p = x + i*16;
  f4 a = ld4(p), b = ld4(p+4), c = ld4(p+8), d = ld4(p+12);
  union { unsigned short u[16]; uint4 q[2]; } U;
  U.u[0]=f16b(a.x); U.u[1]=f16b(a.y); U.u[2]=f16b(a.z); U.u[3]=f16b(a.w);
  U.u[4]=f16b(b.x); U.u[5]=f16b(b.y); U.u[6]=f16b(b.z); U.u[7]=f16b(b.w);
  U.u[8]=f16b(c.x); U.u[9]=f16b(c.y); U.u[10]=f16b(c.z); U.u[11]=f16b(c.w);
  U.u[12]=f16b(d.x);U.u[13]=f16b(d.y);U.u[14]=f16b(d.z); U.u[15]=f16b(d.w);
  *(uint4*)(o + i*16)     = U.q[0];
  *(uint4*)(o + i*16 + 8) = U.q[1];
}

// ---------------- prep: fp32 [R][C] -> bf16 hi/lo [C][R] ----------------
__global__ __launch_bounds__(256)
void prep_transpose(const float* __restrict__ in, unsigned short* __restrict__ oh,
                    unsigned short* __restrict__ ol, int R, int C)
{
  __shared__ float T[32][33];
  const int tx = threadIdx.x & 31, ty = threadIdx.x >> 5;
  const size_t bs = (size_t)R * C;
  const float* ib = in + bs * blockIdx.z;
  unsigned short* ohb = oh + bs * blockIdx.z;
  unsigned short* olb = ol + bs * blockIdx.z;
  const int r0 = blockIdx.y * 32, c0 = blockIdx.x * 32;
  #pragma unroll
  for (int j = 0; j < 4; ++j)
    T[ty + 8*j][tx] = ib[(size_t)(r0 + ty + 8*j)*C + c0 + tx];
  __syncthreads();
  #pragma unroll
  for (int j = 0; j < 4; ++j){
    float v = T[tx][ty + 8*j];
    unsigned short h = bfh(v);
    unsigned short lo = bfh(v - b2f(h));
    size_t o = (size_t)(c0 + ty + 8*j)*R + r0 + tx;
    ohb[o] = h; olb[o] = lo;
  }
}

// ---------------- prep: fp32 [R][C] -> f16 [C][R] ----------------
__global__ __launch_bounds__(256)
void prep_transpose_f16(const float* __restrict__ in, unsigned short* __restrict__ o, int R, int C)
{
  __shared__ float T[32][33];
  const int tx = threadIdx.x & 31, ty = threadIdx.x >> 5;
  const size_t bs = (size_t)R * C;
  const float* ib = in + bs * blockIdx.z;
  unsigned short* ob = o + bs * blockIdx.z;
  const int r0 = blockIdx.y * 32, c0 = blockIdx.x * 32;
  #pragma unroll
  for (int j = 0; j < 4; ++j)
    T[ty + 8*j][tx] = ib[(size_t)(r0 + ty + 8*j)*C + c0 + tx];
  __syncthreads();
  #pragma unroll
  for (int j = 0; j < 4; ++j)
    ob[(size_t)(c0 + ty + 8*j)*R + r0 + tx] = f16b(T[tx][ty + 8*j]);
}

// ================= K1a: GEMM_A  xF16@W1 -> relu -> H1 f16 [TPC][1024] =================
__global__ __launch_bounds__(256, 2)
void gemm_a(const unsigned short* __restrict__ xF, int tok0,
            const unsigned short* __restrict__ W1F,   // [1024][256] f16 (W1^T)
            const float* __restrict__ b1,
            unsigned short* __restrict__ H1)          // chunk-local [TPC][1024] f16
{
  __shared__ unsigned short smem[16384];   // 32 KB
  unsigned short* As = smem;               // [128][64] swizzled
  unsigned short* Bs = smem + 8192;        // [128][64] swizzled
  const int tid = threadIdx.x;
  const int w = tid >> 6, lane = tid & 63, l15 = lane & 15, l4 = lane >> 4;
  const int wm = w >> 1, wn = w & 1;
  // XCD-aware swizzle (T1): nwg=2048 divisible by 8
  const int bid = ((int)blockIdx.x & 7) * ((int)gridDim.x >> 3) + ((int)blockIdx.x >> 3);
  const int mt0 = (bid >> 3) * 128;      // chunk-local token base
  const int nt0 = (bid & 7) * 128;
  const int row_s = tid >> 1, half = tid & 1;
  const int lrow = lane >> 3;
  const int srcAB = lrow*CD + (((lane & 7) ^ lrow) << 3);

  f32x4 acc[4][4];
  #pragma unroll
  for (int mt = 0; mt < 4; ++mt)
    #pragma unroll
    for (int nt = 0; nt < 4; ++nt)
      acc[mt][nt] = (f32x4){0.f,0.f,0.f,0.f};

  #pragma unroll 1
  for (int ks = 0; ks < 4; ++ks){          // K = 256
    const unsigned short* abase = xF  + (size_t)(tok0 + mt0)*CD + ks*64;
    const unsigned short* bbase = W1F + (size_t)nt0*CD + ks*64;
    #pragma unroll
    for (int i = 0; i < 4; ++i){
      const int r0 = w*32 + i*8;
      gload16(abase + (size_t)r0*CD + srcAB, As + r0*64);
      gload16(bbase + (size_t)r0*CD + srcAB, Bs + r0*64);
    }
    __syncthreads();
    #pragma unroll
    for (int kt = 0; kt < 2; ++kt){
      half8 af[4], bf[4];
      #pragma unroll
      for (int mt = 0; mt < 4; ++mt){
        const int r = 64*wm + 16*mt + l15;
        af[mt] = *(const half8*)&As[r*64 + (((kt*4 + l4) ^ (r & 7)) << 3)];
      }
      #pragma unroll
      for (int nt = 0; nt < 4; ++nt){
        const int r = 64*wn + 16*nt + l15;
        bf[nt] = *(const half8*)&Bs[r*64 + (((kt*4 + l4) ^ (r & 7)) << 3)];
      }
      #pragma unroll
      for (int mt = 0; mt < 4; ++mt)
        #pragma unroll
        for (int nt = 0; nt < 4; ++nt)
          acc[mt][nt] = MFMA_HF(af[mt], bf[nt], acc[mt][nt], 0,0,0);
    }
    __syncthreads();
  }

  unsigned short* Cs = smem;               // [128][128]
  #pragma unroll
  for (int nt = 0; nt < 4; ++nt){
    const int ncol = 64*wn + 16*nt + l15;
    const float b1v = b1[nt0 + ncol];
    #pragma unroll
    for (int mt = 0; mt < 4; ++mt)
      #pragma unroll
      for (int r = 0; r < 4; ++r){
        const int tr = 64*wm + 16*mt + 4*l4 + r;
        Cs[tr*128 + ncol] = f16b(fmaxf(acc[mt][nt][r] + b1v, 0.f));
      }
  }
  __syncthreads();
  {
    unsigned short* dst = H1 + (size_t)(mt0 + row_s)*FD + nt0 + half*64;
    const unsigned short* src = Cs + row_s*128 + half*64;
    #pragma unroll
    for (int j = 0; j < 8; ++j) ((uint4*)dst)[j] = ((const uint4*)src)[j];
  }
}

// ================= K1b: GEMM_B  H1@W2 -> relu -> @W3 partial logits =================
__global__ __launch_bounds__(256, 2)
void gemm_b(const unsigned short* __restrict__ H1, int tok0,
            const unsigned short* __restrict__ W2F,   // [1024][1024] f16 (W2^T)
            const float* __restrict__ b2,
            const float* __restrict__ W3,             // [1024][8]
            float* __restrict__ plg)                  // [8][NTOK][8]
{
  __shared__ unsigned short smem[16384];
  unsigned short* As = smem;
  unsigned short* Bs = smem + 8192;
  const int tid = threadIdx.x;
  const int w = tid >> 6, lane = tid & 63, l15 = lane & 15, l4 = lane >> 4;
  const int wm = w >> 1, wn = w & 1;
  const int bid = ((int)blockIdx.x & 7) * ((int)gridDim.x >> 3) + ((int)blockIdx.x >> 3);
  const int ntile = bid & 7;
  const int mt0 = (bid >> 3) * 128;
  const int nt0 = ntile * 128;
  const int row_s = tid >> 1, half = tid & 1;
  const int lrow = lane >> 3;
  const int srcAB = lrow*FD + (((lane & 7) ^ lrow) << 3);

  f32x4 acc[4][4];
  #pragma unroll
  for (int mt = 0; mt < 4; ++mt)
    #pragma unroll
    for (int nt = 0; nt < 4; ++nt)
      acc[mt][nt] = (f32x4){0.f,0.f,0.f,0.f};

  #pragma unroll 1
  for (int ks = 0; ks < 16; ++ks){          // K = 1024
    const unsigned short* abase = H1  + (size_t)mt0*FD + ks*64;
    const unsigned short* bbase = W2F + (size_t)nt0*FD + ks*64;
    #pragma unroll
    for (int i = 0; i < 4; ++i){
      const int r0 = w*32 + i*8;
      gload16(abase + (size_t)r0*FD + srcAB, As + r0*64);
      gload16(bbase + (size_t)r0*FD + srcAB, Bs + r0*64);
    }
    __syncthreads();
    #pragma unroll
    for (int kt = 0; kt < 2; ++kt){
      half8 af[4], bf[4];
      #pragma unroll
      for (int mt = 0; mt < 4; ++mt){
        const int r = 64*wm + 16*mt + l15;
        af[mt] = *(const half8*)&As[r*64 + (((kt*4 + l4) ^ (r & 7)) << 3)];
      }
      #pragma unroll
      for (int nt = 0; nt < 4; ++nt){
        const int r = 64*wn + 16*nt + l15;
        bf[nt] = *(const half8*)&Bs[r*64 + (((kt*4 + l4) ^ (r & 7)) << 3)];
      }
      #pragma unroll
      for (int mt = 0; mt < 4; ++mt)
        #pragma unroll
        for (int nt = 0; nt < 4; ++nt)
          acc[mt][nt] = MFMA_HF(af[mt], bf[nt], acc[mt][nt], 0,0,0);
    }
    __syncthreads();
  }

  float* lgs = (float*)smem;                // 4 KB
  *(f4*)&lgs[tid*4] = (f4){0.f,0.f,0.f,0.f};
  __syncthreads();

  #pragma unroll
  for (int mt = 0; mt < 4; ++mt){           // FULL unroll: static acc index (rule #20)
    float lp[4][8];
    #pragma unroll
    for (int r = 0; r < 4; ++r)
      #pragma unroll
      for (int e = 0; e < 8; ++e) lp[r][e] = 0.f;
    #pragma unroll
    for (int nt = 0; nt < 4; ++nt){
      const int n2 = nt0 + 64*wn + 16*nt + l15;
      const float b2v = b2[n2];
      f4 wa = ld4(W3 + n2*8), wb3 = ld4(W3 + n2*8 + 4);
      const float w3s[8] = {wa.x,wa.y,wa.z,wa.w,wb3.x,wb3.y,wb3.z,wb3.w};
      #pragma unroll
      for (int r = 0; r < 4; ++r){
        float h2 = fmaxf(acc[mt][nt][r] + b2v, 0.f);
        #pragma unroll
        for (int e = 0; e < 8; ++e)
          lp[r][e] = fmaf(h2, w3s[e], lp[r][e]);
      }
    }
    #pragma unroll
    for (int off = 1; off < 16; off <<= 1)
      #pragma unroll
      for (int r = 0; r < 4; ++r)
        #pragma unroll
        for (int e = 0; e < 8; ++e)
          lp[r][e] += __shfl_xor(lp[r][e], off);
    if (l15 == 0){
      #pragma unroll
      for (int r = 0; r < 4; ++r){
        const int row = 64*wm + 16*mt + 4*l4 + r;
        #pragma unroll
        for (int e = 0; e < 8; ++e)
          atomicAdd(&lgs[row*8 + e], lp[r][e]);
      }
    }
  }
  __syncthreads();
  {
    f4 v = *(const f4*)&lgs[row_s*8 + half*4];
    *(f4*)(plg + ((size_t)ntile*NTOK + tok0 + mt0 + row_s)*8 + half*4) = v;
  }
}

// ================= K1c: reduce partial logits, top-2, flag near-ties =================
__global__ __launch_bounds__(256)
void top2_kernel(const float* __restrict__ plg, const float* __restrict__ b3,
                 int2* __restrict__ topE, float2* __restrict__ topW,
                 int* __restrict__ flagList, int* __restrict__ flagCnt)
{
  const int tok = blockIdx.x*256 + threadIdx.x;
  float l[8];
  #pragma unroll
  for (int e = 0; e < 8; ++e) l[e] = b3[e];
  #pragma unroll
  for (int s = 0; s < 8; ++s){
    const float* p = plg + ((size_t)s*NTOK + tok)*8;
    f4 p0 = ld4(p), p1 = ld4(p + 4);
    l[0]+=p0.x; l[1]+=p0.y; l[2]+=p0.z; l[3]+=p0.w;
    l[4]+=p1.x; l[5]+=p1.y; l[6]+=p1.z; l[7]+=p1.w;
  }
  int e1 = 0; float v1 = l[0];
  #pragma unroll
  for (int e = 1; e < 8; ++e){ if (l[e] > v1){ v1 = l[e]; e1 = e; } }
  int e2 = 0; float v2 = -3.0e38f;
  #pragma unroll
  for (int e = 0; e < 8; ++e){ if (e != e1 && l[e] > v2){ v2 = l[e]; e2 = e; } }
  float v3 = -3.0e38f;
  #pragma unroll
  for (int e = 0; e < 8; ++e){ if (e != e1 && e != e2 && l[e] > v3) v3 = l[e]; }
  float s = 0.f;
  #pragma unroll
  for (int e = 0; e < 8; ++e) s += expf(l[e]-v1);
  topE[tok] = make_int2(e1, e2);
  topW[tok] = make_float2(1.0f/s, expf(v2 - v1)/s);
  if (v2 - v3 < 5e-4f){
    int i = atomicAdd(flagCnt, 1);
    if (i < FLAGCAP1) flagList[i] = tok;
  }
}

// ---------------- K2: bf16 3-term re-route of flagged tokens, M=32 ----------------
__global__ __launch_bounds__(512, 2)
void router_fix1(const float* __restrict__ x,
                 const unsigned short* __restrict__ W1Th, const unsigned short* __restrict__ W1Tl,
                 const float* __restrict__ b1,
                 const unsigned short* __restrict__ W2Th, const unsigned short* __restrict__ W2Tl,
                 const float* __restrict__ b2,
                 const float* __restrict__ W3, const float* __restrict__ b3,
                 const int* __restrict__ flagList, const int* __restrict__ flagCnt,
                 int2* __restrict__ topE, float2* __restrict__ topW,
                 int* __restrict__ flagList2, int* __restrict__ flagCnt2)
{
  int cnt = *flagCnt; if (cnt > FLAGCAP1) cnt = FLAGCAP1;
  const int s0 = blockIdx.x * 32;
  if (s0 >= cnt) return;

  __shared__ uint32_t Xp[32*256];
  __shared__ uint32_t Hp[32*128];
  __shared__ float lgs[32*8];
  __shared__ int sTok[32];
  const int tid = threadIdx.x;
  const int w = tid >> 6, lane = tid & 63;
  const int l15 = lane & 15, l4 = lane >> 4;
  const int swz = l15 & 7;

  if (tid < 32){
    const int s = s0 + tid;
    sTok[tid] = (s < cnt) ? flagList[s] : flagList[s0];
  }
  if (tid < 256) lgs[tid] = 0.f;
  __syncthreads();
  {
    const int row = tid >> 4, cb = (tid & 15) * 2;
    const float* rp = x + (size_t)sTok[row]*CD + cb*8;
    #pragma unroll
    for (int g = 0; g < 2; ++g){
      f4 a = ld4(rp + g*8), bq = ld4(rp + g*8 + 4);
      uint32_t* dst = &Xp[row*256 + (((cb + g) ^ (row & 7)) << 3)];
      *(uint4*)dst     = make_uint4(packbf(a.x),packbf(a.y),packbf(a.z),packbf(a.w));
      *(uint4*)(dst+4) = make_uint4(packbf(bq.x),packbf(bq.y),packbf(bq.z),packbf(bq.w));
    }
  }
  __syncthreads();

  f32x4 acc2[2][8];
  #pragma unroll
  for (int mt = 0; mt < 2; ++mt)
    #pragma unroll
    for (int nt = 0; nt < 8; ++nt)
      acc2[mt][nt] = (f32x4){0.f,0.f,0.f,0.f};

  #pragma unroll 1
  for (int kc = 0; kc < 8; ++kc){
    f32x4 acc1[2] = {(f32x4){0,0,0,0},(f32x4){0,0,0,0}};
    const int n1g = kc*128 + 16*w + l15;
    const size_t wb1 = (size_t)n1g * 256;
    #pragma unroll
    for (int kt = 0; kt < 8; ++kt){
      short8 ah[2], al[2];
      #pragma unroll
      for (int mt = 0; mt < 2; ++mt)
        unpack8(&Xp[(mt*16 + l15)*256 + ((((kt<<2) + l4) ^ swz) << 3)], ah[mt], al[mt]);
      const int kb = kt*32 + 8*l4;
      short8 bh = *(const short8*)&W1Th[wb1 + kb];
      short8 bl = *(const short8*)&W1Tl[wb1 + kb];
      #pragma unroll
      for (int mt = 0; mt < 2; ++mt)
        acc1[mt] = MFMA_BF(ah[mt], bh, MFMA_BF(ah[mt], bl, MFMA_BF(al[mt], bh, acc1[mt],0,0,0),0,0,0),0,0,0);
    }
    __syncthreads();
    {
      const float b1v = b1[n1g];
      const int c = 16*w + l15, ch = c >> 3, co = c & 7;
      #pragma unroll
      for (int mt = 0; mt < 2; ++mt)
        #pragma unroll
        for (int r = 0; r < 4; ++r){
          const int row = mt*16 + 4*l4 + r;
          Hp[row*128 + ((ch ^ (row & 7)) << 3) + co] = packbf(fmaxf(acc1[mt][r] + b1v, 0.f));
        }
    }
    __syncthreads();
    #pragma unroll
    for (int kt = 0; kt < 4; ++kt){
      short8 ah[2], al[2];
      #pragma unroll
      for (int mt = 0; mt < 2; ++mt)
        unpack8(&Hp[(mt*16 + l15)*128 + ((((kt<<2) + l4) ^ swz) << 3)], ah[mt], al[mt]);
      const size_t kg = (size_t)(kc*128 + kt*32 + 8*l4);
      #pragma unroll
      for (int nt = 0; nt < 8; ++nt){
        const size_t wb2 = (size_t)(128*w + 16*nt + l15) * 1024 + kg;
        short8 bh = *(const short8*)&W2Th[wb2];
        short8 bl = *(const short8*)&W2Tl[wb2];
        #pragma unroll
        for (int mt = 0; mt < 2; ++mt)
          acc2[mt][nt] = MFMA_BF(ah[mt], bh, MFMA_BF(ah[mt], bl, MFMA_BF(al[mt], bh, acc2[mt][nt],0,0,0),0,0,0),0,0,0);
      }
    }
  }

  #pragma unroll
  for (int mt = 0; mt < 2; ++mt){
    float lp[4][8];
    #pragma unroll
    for (int r = 0; r < 4; ++r)
      #pragma unroll
      for (int e = 0; e < 8; ++e) lp[r][e] = 0.f;
    #pragma unroll
    for (int nt = 0; nt < 8; ++nt){
      const int n2 = 128*w + 16*nt + l15;
      const float b2v = b2[n2];
      f4 wa = ld4(W3 + n2*8), wb3 = ld4(W3 + n2*8 + 4);
      const float w3s[8] = {wa.x,wa.y,wa.z,wa.w,wb3.x,wb3.y,wb3.z,wb3.w};
      #pragma unroll
      for (int r = 0; r < 4; ++r){
        float h2 = fmaxf(acc2[mt][nt][r] + b2v, 0.f);
        #pragma unroll
        for (int e = 0; e < 8; ++e)
          lp[r][e] = fmaf(h2, w3s[e], lp[r][e]);
      }
    }
    #pragma unroll
    for (int off = 1; off < 16; off <<= 1)
      #pragma unroll
      for (int r = 0; r < 4; ++r)
        #pragma unroll
        for (int e = 0; e < 8; ++e)
          lp[r][e] += __shfl_xor(lp[r][e], off);
    if (l15 == 0){
      #pragma unroll
      for (int r = 0; r < 4; ++r){
        const int row = mt*16 + 4*l4 + r;
        #pragma unroll
        for (int e = 0; e < 8; ++e)
          atomicAdd(&lgs[row*8 + e], lp[r][e]);
      }
    }
  }
  __syncthreads();

  if (tid < 32 && s0 + tid < cnt){
    const int tok = sTok[tid];
    float l[8];
    #pragma unroll
    for (int e = 0; e < 8; ++e) l[e] = lgs[tid*8 + e] + b3[e];
    int e1 = 0; float v1 = l[0];
    #pragma unroll
    for (int e = 1; e < 8; ++e){ if (l[e] > v1){ v1 = l[e]; e1 = e; } }
    int e2 = 0; float v2 = -3.0e38f;
    #pragma unroll
    for (int e = 0; e < 8; ++e){ if (e != e1 && l[e] > v2){ v2 = l[e]; e2 = e; } }
    float v3 = -3.0e38f;
    #pragma unroll
    for (int e = 0; e < 8; ++e){ if (e != e1 && e != e2 && l[e] > v3) v3 = l[e]; }
    float s = 0.f;
    #pragma unroll
    for (int e = 0; e < 8; ++e) s += expf(l[e]-v1);
    topE[tok] = make_int2(e1, e2);
    topW[tok] = make_float2(1.0f/s, expf(v2 - v1)/s);
    if (v2 - v3 < 1e-4f){
      int i = atomicAdd(flagCnt2, 1);
      if (i < FLAGCAP2) flagList2[i] = tok;
    }
  }
}

// ---------------- K3: exact fp32 recompute for residual near-ties ----------------
__global__ __launch_bounds__(256)
void router_fixup(const float* __restrict__ x,
                  const float* __restrict__ W1, const float* __restrict__ b1,
                  const float* __restrict__ W2, const float* __restrict__ b2,
                  const float* __restrict__ W3, const float* __restrict__ b3,
                  const int* __restrict__ flagList, const int* __restrict__ flagCnt,
                  int2* __restrict__ topE, float2* __restrict__ topW)
{
  int n = *flagCnt; if (n > FLAGCAP2) n = FLAGCAP2;
  if ((int)blockIdx.x >= n) return;
  const int t = flagList[blockIdx.x];
  __shared__ float xs[256];
  __shared__ float h1[1024];
  __shared__ float h2[1024];
  __shared__ float lgf[8];
  const int tid = threadIdx.x;
  xs[tid] = x[(size_t)t*256 + tid];
  __syncthreads();
  {
    float a0=b1[tid], a1=b1[tid+256], a2=b1[tid+512], a3=b1[tid+768];
    for (int k = 0; k < 256; ++k){
      const float xv = xs[k];
      const float* wr = W1 + (size_t)k*1024;
      a0 = fmaf(xv, wr[tid],     a0);
      a1 = fmaf(xv, wr[tid+256], a1);
      a2 = fmaf(xv, wr[tid+512], a2);
      a3 = fmaf(xv, wr[tid+768], a3);
    }
    h1[tid]=fmaxf(a0,0.f); h1[tid+256]=fmaxf(a1,0.f); h1[tid+512]=fmaxf(a2,0.f); h1[tid+768]=fmaxf(a3,0.f);
  }
  __syncthreads();
  {
    float a0=b2[tid], a1=b2[tid+256], a2=b2[tid+512], a3=b2[tid+768];
    for (int k = 0; k < 1024; ++k){
      const float hv = h1[k];
      const float* wr = W2 + (size_t)k*1024;
      a0 = fmaf(hv, wr[tid],     a0);
      a1 = fmaf(hv, wr[tid+256], a1);
      a2 = fmaf(hv, wr[tid+512], a2);
      a3 = fmaf(hv, wr[tid+768], a3);
    }
    h2[tid]=fmaxf(a0,0.f); h2[tid+256]=fmaxf(a1,0.f); h2[tid+512]=fmaxf(a2,0.f); h2[tid+768]=fmaxf(a3,0.f);
  }
  __syncthreads();
  {
    const int e = tid >> 5, s = tid & 31;
    float p = 0.f;
    for (int k = s*32; k < s*32+32; ++k) p = fmaf(h2[k], W3[(size_t)k*8 + e], p);
    #pragma unroll
    for (int off = 1; off < 32; off <<= 1) p += __shfl_xor(p, off);
    if (s == 0) lgf[e] = p + b3[e];
  }
  __syncthreads();
  if (tid == 0){
    float l[8];
    #pragma unroll
    for (int e=0;e<8;++e) l[e] = lgf[e];
    int e1 = 0; float v1 = l[0];
    #pragma unroll
    for (int e=1;e<8;++e){ if (l[e] > v1){ v1 = l[e]; e1 = e; } }
    int e2 = 0; float v2 = -3.0e38f;
    #pragma unroll
    for (int e=0;e<8;++e){ if (e != e1 && l[e] > v2){ v2 = l[e]; e2 = e; } }
    float s = 0.f;
    #pragma unroll
    for (int e=0;e<8;++e) s += expf(l[e]-v1);
    topE[t] = make_int2(e1, e2);
    topW[t] = make_float2(1.0f/s, expf(v2 - v1)/s);
  }
}

// ---------------- K4: per-(b,e) count, capacity mask, stable compaction ----------------
__global__ __launch_bounds__(256)
void route_compact(const int2* __restrict__ topE, const float2* __restrict__ topW,
                   int* __restrict__ listIdx, float* __restrict__ listW, int* __restrict__ kcnt)
{
  const int blk = blockIdx.x;
  const int b = blk >> 3, e = blk & 7;
  const int2* te = topE + (size_t)b*TT;
  const float2* tw = topW + (size_t)b*TT;
  __shared__ unsigned kmask[256];
  __shared__ int wTot[4], wTot2[4];
  __shared__ int s_cnt, s_baseRank, s_baseSlot;
  const int tid = threadIdx.x;
  const int lane = tid & 63, wid = tid >> 6;

  if (tid == 0){ s_cnt = 0; s_baseRank = 0; s_baseSlot = 0; }
  kmask[tid & 255] = 0;
  __syncthreads();

  int c = 0;
  for (int t = tid; t < TT; t += 256){
    int2 v = te[t];
    c += (v.x == e) || (v.y == e);
  }
  #pragma unroll
  for (int off = 32; off; off >>= 1) c += __shfl_xor(c, off);
  if (lane == 0) atomicAdd(&s_cnt, c);
  __syncthreads();
  const int cnt = s_cnt;

  if (cnt > CAPY){
    for (int i = tid; i < CAPY; i += 256){
      float t1 = (float)i * (float)(cnt - 1);
      float t2 = t1 / 1279.0f;
      int r = (int)floorf(t2);
      atomicOr(&kmask[r >> 5], 1u << (r & 31));
    }
  }
  __syncthreads();

  for (int tile = 0; tile < 32; ++tile){
    const int t = tile*256 + tid;
    const int2 v = te[t];
    const bool sel = (v.x == e) || (v.y == e);
    const float2 wv = tw[t];
    const float w = (v.x == e) ? wv.x : wv.y;

    unsigned long long mSel = __ballot(sel);
    const int lpfx = __popcll(mSel & ((1ull << lane) - 1ull));
    if (lane == 0) wTot[wid] = __popcll(mSel);
    __syncthreads();
    int wpfx = 0;
    for (int wdx = 0; wdx < wid; ++wdx) wpfx += wTot[wdx];
    const int rank = s_baseRank + wpfx + lpfx;

    const bool kept = sel && (cnt <= CAPY || ((kmask[rank >> 5] >> (rank & 31)) & 1u));
    unsigned long long mK = __ballot(kept);
    const int lpfx2 = __popcll(mK & ((1ull << lane) - 1ull));
    if (lane == 0) wTot2[wid] = __popcll(mK);
    __syncthreads();
    int wpfx2 = 0;
    for (int wdx = 0; wdx < wid; ++wdx) wpfx2 += wTot2[wdx];
    const int slot = s_baseSlot + wpfx2 + lpfx2;

    if (kept){
      listIdx[(size_t)blk*CAPY + slot] = t;
      listW [(size_t)blk*CAPY + slot] = w;
    }
    __syncthreads();
    if (tid == 0){
      int a = 0, q = 0;
      for (int wdx = 0; wdx < 4; ++wdx){ a += wTot[wdx]; q += wTot2[wdx]; }
      s_baseRank += a; s_baseSlot += q;
    }
    __syncthreads();
  }
  if (tid == 0) kcnt[blk] = s_baseSlot;
}

// ---------------- K5: expert FFN, M=64, f16 MFMA, e-major grid ----------------
__global__ __launch_bounds__(512, 2)
void expert_mfma(const float* __restrict__ x,
                 const unsigned short* __restrict__ WiF, const float* __restrict__ ebi,
                 const unsigned short* __restrict__ WoF, const float* __restrict__ ebo,
                 const int* __restrict__ listIdx, const float* __restrict__ listW,
                 const int* __restrict__ kcnt, float* __restrict__ out)
{
  const int q = blockIdx.y;
  const int e = q >> 4, b = q & 15;
  const int pair = b*8 + e;
  const int kc_n = kcnt[pair];
  const int s0 = blockIdx.x * 64;
  if (s0 >= kc_n) return;

  __shared__ unsigned short Xf[64*256];
  __shared__ unsigned short Hf[64*128];
  __shared__ int sTok[64];
  __shared__ float sG[64];
  const int tid = threadIdx.x;
  const int w = tid >> 6, lane = tid & 63;
  const int l15 = lane & 15, l4 = lane >> 4;
  const int swz = l15 & 7;

  if (tid < 64){
    const int s = s0 + tid;
    const bool v = s < kc_n;
    sTok[tid] = v ? listIdx[(size_t)pair*CAPY + s] : -1;
    sG[tid]   = v ? listW [(size_t)pair*CAPY + s] : 0.f;
  }
  __syncthreads();
  {
    const int row = tid >> 3, cb = (tid & 7) * 4;
    int tk = sTok[row]; if (tk < 0) tk = 0;
    const float* rp = x + ((size_t)b*TT + tk)*CD + cb*8;
    #pragma unroll
    for (int g = 0; g < 4; ++g){
      f4 a = ld4(rp + g*8), bq = ld4(rp + g*8 + 4);
      union { unsigned short u[8]; short8 s; } U;
      U.u[0]=f16b(a.x); U.u[1]=f16b(a.y); U.u[2]=f16b(a.z); U.u[3]=f16b(a.w);
      U.u[4]=f16b(bq.x);U.u[5]=f16b(bq.y);U.u[6]=f16b(bq.z);U.u[7]=f16b(bq.w);
      *(short8*)&Xf[row*256 + (((cb + g) ^ (row & 7)) << 3)] = U.s;
    }
  }
  __syncthreads();

  const unsigned short* Wi = WiF + (size_t)e*FD*CD;
  const unsigned short* Wo = WoF + (size_t)e*CD*FD;

  f32x4 accO[4][2];
  #pragma unroll
  for (int mt = 0; mt < 4; ++mt)
    #pragma unroll
    for (int nt = 0; nt < 2; ++nt)
      accO[mt][nt] = (f32x4){0.f,0.f,0.f,0.f};

  #pragma unroll 1
  for (int kc = 0; kc < 8; ++kc){
    f32x4 acc1[4] = {(f32x4){0,0,0,0},(f32x4){0,0,0,0},(f32x4){0,0,0,0},(f32x4){0,0,0,0}};
    const int n1g = kc*128 + 16*w + l15;
    const size_t wbi = (size_t)n1g * 256;
    #pragma unroll
    for (int kt = 0; kt < 8; ++kt){
      half8 av[4];
      #pragma unroll
      for (int mt = 0; mt < 4; ++mt)
        av[mt] = *(const half8*)&Xf[(mt*16 + l15)*256 + ((((kt<<2) + l4) ^ swz) << 3)];
      half8 bf = *(const half8*)&Wi[wbi + kt*32 + 8*l4];
      #pragma unroll
      for (int mt = 0; mt < 4; ++mt)
        acc1[mt] = MFMA_HF(av[mt], bf, acc1[mt], 0,0,0);
    }
    __syncthreads();
    {
      const float biv = ebi[e*FD + n1g];
      const int c = 16*w + l15, ch = c >> 3, co = c & 7;
      #pragma unroll
      for (int mt = 0; mt < 4; ++mt)
        #pragma unroll
        for (int r = 0; r < 4; ++r){
          const int row = mt*16 + 4*l4 + r;
          Hf[row*128 + ((ch ^ (row & 7)) << 3) + co] = f16b(fmaxf(acc1[mt][r] + biv, 0.f));
        }
    }
    __syncthreads();
    #pragma unroll
    for (int kt = 0; kt < 4; ++kt){
      half8 av[4];
      #pragma unroll
      for (int mt = 0; mt < 4; ++mt)
        av[mt] = *(const half8*)&Hf[(mt*16 + l15)*128 + ((((kt<<2) + l4) ^ swz) << 3)];
      const size_t kg = (size_t)(kc*128 + kt*32 + 8*l4);
      #pragma unroll
      for (int nt = 0; nt < 2; ++nt){
        const int n = 32*w + 16*nt + l15;
        half8 bf = *(const half8*)&Wo[(size_t)n*1024 + kg];
        #pragma unroll
        for (int mt = 0; mt < 4; ++mt)
          accO[mt][nt] = MFMA_HF(av[mt], bf, accO[mt][nt], 0,0,0);
      }
    }
  }

  #pragma unroll
  for (int mt = 0; mt < 4; ++mt)
    #pragma unroll
    for (int r = 0; r < 4; ++r){
      const int row = mt*16 + 4*l4 + r;
      const int tk = sTok[row];
      if (tk >= 0){
        const float g = sG[row];
        #pragma unroll
        for (int nt = 0; nt < 2; ++nt){
          const int n = 32*w + 16*nt + l15;
          atomicAdd(out + ((size_t)b*TT + tk)*CD + n, (accO[mt][nt][r] + ebo[e*CD + n]) * g);
        }
      }
    }
}

} // namespace

extern "C" void kernel_launch(void* const* d_in, const int* in_sizes, int n_in,
                              void* d_out, int out_size, void* d_ws, size_t ws_size,
                              hipStream_t stream)
{
  const float* x   = (const float*)d_in[0];
  const float* rW1 = (const float*)d_in[1];
  const float* rb1 = (const float*)d_in[2];
  const float* rW2 = (const float*)d_in[3];
  const float* rb2 = (const float*)d_in[4];
  const float* rW3 = (const float*)d_in[5];
  const float* rb3 = (const float*)d_in[6];
  const float* eWi = (const float*)d_in[7];
  const float* ebi = (const float*)d_in[8];
  const float* eWo = (const float*)d_in[9];
  const float* ebo = (const float*)d_in[10];
  (void)in_sizes; (void)n_in; (void)ws_size;

  char* ws = (char*)d_ws;
  size_t off = 0;
  auto carve = [&](size_t bytes)->char*{ char* p = ws + off; off += (bytes + 255) & ~(size_t)255; return p; };
  unsigned short* W1F  = (unsigned short*)carve((size_t)FD*CD*2);
  unsigned short* W2F  = (unsigned short*)carve((size_t)FD*FD*2);
  unsigned short* W1Th = (unsigned short*)carve((size_t)FD*CD*2);
  unsigned short* W1Tl = (unsigned short*)carve((size_t)FD*CD*2);
  unsigned short* W2Th = (unsigned short*)carve((size_t)FD*FD*2);
  unsigned short* W2Tl = (unsigned short*)carve((size_t)FD*FD*2);
  unsigned short* WiF  = (unsigned short*)carve((size_t)8*FD*CD*2);
  unsigned short* WoF  = (unsigned short*)carve((size_t)8*CD*FD*2);
  unsigned short* xF16 = (unsigned short*)carve((size_t)NTOK*CD*2);         // 67 MB
  unsigned short* H1   = (unsigned short*)carve((size_t)TPC*FD*2);          // 67 MB
  float*  plg     = (float*)carve((size_t)8*NTOK*8*sizeof(float));          // 33.5 MB
  int2*   topE    = (int2*)carve((size_t)NTOK*sizeof(int2));
  float2* topW    = (float2*)carve((size_t)NTOK*sizeof(float2));
  int*    listIdx = (int*)carve((size_t)NPAIR*CAPY*sizeof(int));
  float*  listW   = (float*)carve((size_t)NPAIR*CAPY*sizeof(float));
  int*    kcnt    = (int*)carve((size_t)NPAIR*sizeof(int));
  int*    flagCnt = (int*)carve(256);
  int*    flagCnt2= (int*)carve(256);
  int*    flagList= (int*)carve((size_t)FLAGCAP1*sizeof(int));
  int*    flagList2=(int*)carve((size_t)FLAGCAP2*sizeof(int));

  float* out = (float*)d_out;
  hipMemsetAsync(out, 0, (size_t)out_size*sizeof(float), stream);
  hipMemsetAsync(flagCnt, 0, sizeof(int), stream);
  hipMemsetAsync(flagCnt2, 0, sizeof(int), stream);

  x_to_f16<<<NTOK*CD/16/256, 256, 0, stream>>>(x, xF16);
  prep_transpose_f16<<<dim3(32, 8, 1), 256, 0, stream>>>(rW1, W1F, 256, 1024);
  prep_transpose_f16<<<dim3(32,32, 1), 256, 0, stream>>>(rW2, W2F, 1024, 1024);
  prep_transpose<<<dim3(32, 8, 1), 256, 0, stream>>>(rW1, W1Th, W1Tl, 256, 1024);
  prep_transpose<<<dim3(32,32, 1), 256, 0, stream>>>(rW2, W2Th, W2Tl, 1024, 1024);
  prep_transpose_f16<<<dim3(32, 8, 8), 256, 0, stream>>>(eWi, WiF, 256, 1024);
  prep_transpose_f16<<<dim3( 8,32, 8), 256, 0, stream>>>(eWo, WoF, 1024, 256);

  for (int c = 0; c < NCHUNK; ++c){
    gemm_a<<<(TPC/128)*8, 256, 0, stream>>>(xF16, c*TPC, W1F, rb1, H1);
    gemm_b<<<(TPC/128)*8, 256, 0, stream>>>(H1, c*TPC, W2F, rb2, rW3, plg);
  }
  top2_kernel<<<NTOK/256, 256, 0, stream>>>(plg, rb3, topE, topW, flagList, flagCnt);

  router_fix1<<<FLAGCAP1/32, 512, 0, stream>>>(x, W1Th, W1Tl, rb1, W2Th, W2Tl, rb2,
                                               rW3, rb3, flagList, flagCnt,
                                               topE, topW, flagList2, flagCnt2);
  router_fixup<<<FLAGCAP2, 256, 0, stream>>>(x, rW1, rb1, rW2, rb2, rW3, rb3,
                                             flagList2, flagCnt2, topE, topW);
  route_compact<<<NPAIR, 256, 0, stream>>>(topE, topW, listIdx, listW, kcnt);
  expert_mfma<<<dim3(CAPY/64, 128), 512, 0, stream>>>(x, WiF, ebi, WoF, ebo,
                                                      listIdx, listW, kcnt, out);
}